// Round 1
// baseline (592.982 us; speedup 1.0000x reference)
//
#include <hip/hip_runtime.h>
#include <math.h>

// GAT aggregator: embed-gather -> GAT layer1 -> GAT layer2 -> per-graph max pool.
// h=64, H=3 heads fixed by the problem; N, E taken from in_sizes.

#define HEADS 3
#define HD 64          // hidden dim per head == h
#define FDIM (HEADS*HD) // 192
#define NUM_GRAPHS 10
#define FEAT_NPB 16    // nodes per block in feat kernel

// ---------------- wave helpers ----------------
__device__ __forceinline__ int wave_incl_scan(int v, int lane) {
#pragma unroll
    for (int off = 1; off < 64; off <<= 1) {
        int t = __shfl_up(v, off);
        if (lane >= off) v += t;
    }
    return v;
}

// monotone float<->uint mapping for atomicMax on floats (handles negatives)
__device__ __forceinline__ unsigned int fmap(float f) {
    unsigned int u = __float_as_uint(f);
    return (u & 0x80000000u) ? ~u : (u | 0x80000000u);
}
__device__ __forceinline__ float funmap(unsigned int u) {
    u = (u & 0x80000000u) ? (u & 0x7FFFFFFFu) : ~u;
    return __uint_as_float(u);
}

// ---------------- CSR build ----------------
__global__ void k_hist(const int* __restrict__ dst, int* __restrict__ deg, int E) {
    int i = blockIdx.x * blockDim.x + threadIdx.x;
    if (i < E) atomicAdd(&deg[dst[i]], 1);
}

__global__ void k_scan1(const int* __restrict__ deg, int* __restrict__ tmp,
                        int* __restrict__ partials, int N) {
    int t = threadIdx.x, b = blockIdx.x;
    int i = b * 256 + t;
    int v = (i < N) ? deg[i] : 0;
    int lane = t & 63, w = t >> 6;
    int incl = wave_incl_scan(v, lane);
    __shared__ int wsum[4];
    if (lane == 63) wsum[w] = incl;
    __syncthreads();
    int off = 0;
    for (int j = 0; j < w; ++j) off += wsum[j];
    incl += off;
    if (i < N) tmp[i] = incl;
    if (t == 255) partials[b] = incl;
}

__global__ void k_scan2(int* __restrict__ partials, int nb) {
    int t = threadIdx.x;                   // 512 threads, nb <= 512
    int v = (t < nb) ? partials[t] : 0;
    int lane = t & 63, w = t >> 6;
    int incl = wave_incl_scan(v, lane);
    __shared__ int wsum[8];
    if (lane == 63) wsum[w] = incl;
    __syncthreads();
    int off = 0;
    for (int j = 0; j < w; ++j) off += wsum[j];
    incl += off;
    if (t < nb) partials[t] = incl;
}

__global__ void k_scan3(const int* __restrict__ tmp, const int* __restrict__ deg,
                        const int* __restrict__ partials, int* __restrict__ rowptr,
                        int* __restrict__ cur, int N) {
    int i = blockIdx.x * blockDim.x + threadIdx.x;
    if (i >= N) return;
    int b = i >> 8;
    int off = b ? partials[b - 1] : 0;
    int incl = tmp[i] + off;
    rowptr[i + 1] = incl;
    cur[i] = incl - deg[i];
    if (i == 0) rowptr[0] = 0;
}

__global__ void k_scatter(const int* __restrict__ src, const int* __restrict__ dst,
                          int* __restrict__ cur, int* __restrict__ csrc, int E) {
    int i = blockIdx.x * blockDim.x + threadIdx.x;
    if (i >= E) return;
    int pos = atomicAdd(&cur[dst[i]], 1);
    csrc[pos] = src[i];
}

// ---------------- feat = x @ W, plus el/er ----------------
// block = 192 threads = 3 waves (wave == head). Each thread keeps its W column
// (64 floats) in VGPRs; 16 nodes staged in LDS per block.
__global__ __launch_bounds__(192) void k_feat(
        const float* __restrict__ xin, const int* __restrict__ ids,
        const float* __restrict__ Wemb, const float* __restrict__ W,
        const float* __restrict__ al, const float* __restrict__ ar,
        float* __restrict__ feat, float* __restrict__ el, float* __restrict__ er,
        int N) {
    int t = threadIdx.x;
    int hd = t >> 6, d = t & 63;
    float wcol[64];
#pragma unroll
    for (int k = 0; k < 64; ++k) wcol[k] = W[k * FDIM + t];
    float a_l = al[hd * HD + d], a_r = ar[hd * HD + d];

    __shared__ float xs[FEAT_NPB][HD];
    int base = blockIdx.x * FEAT_NPB;
    for (int i = t; i < FEAT_NPB * HD; i += 192) {
        int n = base + (i >> 6);
        int c = i & 63;
        float v = 0.f;
        if (n < N) v = ids ? Wemb[(size_t)ids[n] * HD + c] : xin[(size_t)n * HD + c];
        xs[i >> 6][c] = v;
    }
    __syncthreads();

    for (int i = 0; i < FEAT_NPB; ++i) {
        int n = base + i;
        if (n >= N) break;
        const float4* xv4 = (const float4*)xs[i];
        float acc = 0.f;
#pragma unroll
        for (int k4 = 0; k4 < 16; ++k4) {
            float4 xv = xv4[k4];
            acc = fmaf(xv.x, wcol[4 * k4 + 0], acc);
            acc = fmaf(xv.y, wcol[4 * k4 + 1], acc);
            acc = fmaf(xv.z, wcol[4 * k4 + 2], acc);
            acc = fmaf(xv.w, wcol[4 * k4 + 3], acc);
        }
        feat[(size_t)n * FDIM + t] = acc;
        float pl = acc * a_l, pr = acc * a_r;
#pragma unroll
        for (int off = 32; off; off >>= 1) {
            pl += __shfl_down(pl, off);
            pr += __shfl_down(pr, off);
        }
        if (d == 0) { el[n * HEADS + hd] = pl; er[n * HEADS + hd] = pr; }
    }
}

// ---------------- gather aggregation + finalize (edge softmax, fused) ---------
// one wave per node, lane = d. Loops incoming edges via CSR.
__global__ void k_gather_agg(const int* __restrict__ rowptr, const int* __restrict__ csrc,
                             const float* __restrict__ el, const float* __restrict__ er,
                             const float* __restrict__ feat, const float* __restrict__ b,
                             float* __restrict__ xout, int N) {
    int wid = (blockIdx.x * blockDim.x + threadIdx.x) >> 6; // node
    int lane = threadIdx.x & 63;
    if (wid >= N) return;
    int beg = rowptr[wid], end = rowptr[wid + 1];
    float er0 = er[wid * HEADS + 0];
    float er1 = er[wid * HEADS + 1];
    float er2 = er[wid * HEADS + 2];
    float acc0 = 0.f, acc1 = 0.f, acc2 = 0.f;
    float ds0 = 0.f, ds1 = 0.f, ds2 = 0.f;
    for (int j = beg; j < end; ++j) {
        int s = csrc[j];
        const float* frow = feat + (size_t)s * FDIM;
        float e0 = el[s * HEADS + 0] + er0; e0 = e0 >= 0.f ? e0 : 0.2f * e0;
        float e1 = el[s * HEADS + 1] + er1; e1 = e1 >= 0.f ? e1 : 0.2f * e1;
        float e2 = el[s * HEADS + 2] + er2; e2 = e2 >= 0.f ? e2 : 0.2f * e2;
        float w0 = __expf(e0), w1 = __expf(e1), w2 = __expf(e2);
        acc0 = fmaf(w0, frow[lane], acc0);
        acc1 = fmaf(w1, frow[HD + lane], acc1);
        acc2 = fmaf(w2, frow[2 * HD + lane], acc2);
        ds0 += w0; ds1 += w1; ds2 += w2;
    }
    float o = (acc0 / fmaxf(ds0, 1e-9f) + b[lane])
            + (acc1 / fmaxf(ds1, 1e-9f) + b[HD + lane])
            + (acc2 / fmaxf(ds2, 1e-9f) + b[2 * HD + lane]);
    xout[(size_t)wid * HD + lane] = o * (1.f / 3.f);
}

// ---------------- per-graph max pooling ----------------
__global__ void k_gmax_init(unsigned int* __restrict__ gm) {
    int i = blockIdx.x * blockDim.x + threadIdx.x;
    if (i < NUM_GRAPHS * HD) gm[i] = 0x007FFFFFu; // fmap(-inf)
}

__global__ void k_gmax(const float* __restrict__ x, const int* __restrict__ gid,
                       unsigned int* __restrict__ gm, int N) {
    int lane = threadIdx.x; // 64 threads, lane = d
    int base = blockIdx.x * 64;
    int endn = min(base + 64, N);
    int cur = -1;
    float m = 0.f;
    for (int n = base; n < endn; ++n) {
        int g = gid[n];
        float v = x[(size_t)n * HD + lane];
        if (g != cur) {
            if (cur >= 0) atomicMax(&gm[cur * HD + lane], fmap(m));
            cur = g; m = v;
        } else {
            m = fmaxf(m, v);
        }
    }
    if (cur >= 0) atomicMax(&gm[cur * HD + lane], fmap(m));
}

__global__ void k_gmax_final(const unsigned int* __restrict__ gm, float* __restrict__ out) {
    int i = blockIdx.x * blockDim.x + threadIdx.x;
    if (i < NUM_GRAPHS * HD) out[i] = funmap(gm[i]);
}

// ---------------- launch ----------------
extern "C" void kernel_launch(void* const* d_in, const int* in_sizes, int n_in,
                              void* d_out, int out_size, void* d_ws, size_t ws_size,
                              hipStream_t stream) {
    const int*   node_ids = (const int*)d_in[0];
    const int*   edge_src = (const int*)d_in[1];
    const int*   edge_dst = (const int*)d_in[2];
    const int*   gid      = (const int*)d_in[3];
    const float* Wemb     = (const float*)d_in[4];
    const float* W1  = (const float*)d_in[5];
    const float* al1 = (const float*)d_in[6];
    const float* ar1 = (const float*)d_in[7];
    const float* b1  = (const float*)d_in[8];
    const float* W2  = (const float*)d_in[9];
    const float* al2 = (const float*)d_in[10];
    const float* ar2 = (const float*)d_in[11];
    const float* b2  = (const float*)d_in[12];

    int N = in_sizes[0];
    int E = in_sizes[1];

    // workspace layout
    char* p = (char*)d_ws;
    auto alloc = [&](size_t bytes) {
        char* r = p;
        p += (bytes + 255) & ~(size_t)255;
        return (void*)r;
    };
    int*   deg      = (int*)alloc((size_t)N * 4);
    int*   tmp      = (int*)alloc((size_t)N * 4);
    int*   partials = (int*)alloc(512 * 4);
    int*   rowptr   = (int*)alloc((size_t)(N + 1) * 4);
    int*   cur      = (int*)alloc((size_t)N * 4);
    int*   csrc     = (int*)alloc((size_t)E * 4);
    float* feat     = (float*)alloc((size_t)N * FDIM * 4);
    float* el       = (float*)alloc((size_t)N * HEADS * 4);
    float* er       = (float*)alloc((size_t)N * HEADS * 4);
    float* x1       = (float*)alloc((size_t)N * HD * 4);
    unsigned int* gm = (unsigned int*)alloc(NUM_GRAPHS * HD * 4);
    (void)ws_size;

    // ---- CSR build (by dst) ----
    hipMemsetAsync(deg, 0, (size_t)N * 4, stream);
    k_hist<<<dim3((E + 255) / 256), dim3(256), 0, stream>>>(edge_dst, deg, E);
    int nb = (N + 255) / 256;
    k_scan1<<<dim3(nb), dim3(256), 0, stream>>>(deg, tmp, partials, N);
    k_scan2<<<dim3(1), dim3(512), 0, stream>>>(partials, nb);
    k_scan3<<<dim3((N + 255) / 256), dim3(256), 0, stream>>>(tmp, deg, partials, rowptr, cur, N);
    k_scatter<<<dim3((E + 255) / 256), dim3(256), 0, stream>>>(edge_src, edge_dst, cur, csrc, E);

    dim3 featGrid((N + FEAT_NPB - 1) / FEAT_NPB), featBlk(192);
    dim3 aggGrid((N * 64 + 255) / 256), aggBlk(256);

    // ---- layer 1 (x = embedding gather, fused) ----
    k_feat<<<featGrid, featBlk, 0, stream>>>(nullptr, node_ids, Wemb, W1, al1, ar1,
                                             feat, el, er, N);
    k_gather_agg<<<aggGrid, aggBlk, 0, stream>>>(rowptr, csrc, el, er, feat, b1, x1, N);

    // ---- layer 2 ----
    k_feat<<<featGrid, featBlk, 0, stream>>>(x1, nullptr, nullptr, W2, al2, ar2,
                                             feat, el, er, N);
    k_gather_agg<<<aggGrid, aggBlk, 0, stream>>>(rowptr, csrc, el, er, feat, b2, x1, N);

    // ---- per-graph max pooling ----
    k_gmax_init<<<dim3(1), dim3(NUM_GRAPHS * HD), 0, stream>>>(gm);
    k_gmax<<<dim3((N + 63) / 64), dim3(64), 0, stream>>>(x1, gid, gm, N);
    k_gmax_final<<<dim3(1), dim3(NUM_GRAPHS * HD), 0, stream>>>(gm, (float*)d_out);
}

// Round 2
// 500.824 us; speedup vs baseline: 1.1840x; 1.1840x over previous
//
#include <hip/hip_runtime.h>
#include <math.h>

// GAT aggregator: embed-gather -> GAT layer1 -> GAT layer2 -> per-graph max pool.
// h=64, H=3 heads fixed by the problem; N, E taken from in_sizes.
// feat stored as bf16 (halves the dominant gather stream); all accumulation fp32.

#define HEADS 3
#define HD 64          // hidden dim per head == h
#define FDIM (HEADS*HD) // 192
#define NUM_GRAPHS 10
#define FEAT_NPB 16    // nodes per block in feat kernel

// ---------------- bf16 helpers (manual, exact) ----------------
__device__ __forceinline__ float bf2f(unsigned short u) {
    return __uint_as_float(((unsigned int)u) << 16);
}
__device__ __forceinline__ unsigned short f2bf(float f) {
    unsigned int u = __float_as_uint(f);
    unsigned int r = (u + 0x7FFFu + ((u >> 16) & 1u)) >> 16;  // round-nearest-even
    return (unsigned short)r;
}

// ---------------- wave helpers ----------------
__device__ __forceinline__ int wave_incl_scan(int v, int lane) {
#pragma unroll
    for (int off = 1; off < 64; off <<= 1) {
        int t = __shfl_up(v, off);
        if (lane >= off) v += t;
    }
    return v;
}

// monotone float<->uint mapping for atomicMax on floats (handles negatives)
__device__ __forceinline__ unsigned int fmap(float f) {
    unsigned int u = __float_as_uint(f);
    return (u & 0x80000000u) ? ~u : (u | 0x80000000u);
}
__device__ __forceinline__ float funmap(unsigned int u) {
    u = (u & 0x80000000u) ? (u & 0x7FFFFFFFu) : ~u;
    return __uint_as_float(u);
}

// ---------------- CSR build ----------------
__global__ void k_hist(const int* __restrict__ dst, int* __restrict__ deg, int E) {
    int i = blockIdx.x * blockDim.x + threadIdx.x;
    if (i < E) atomicAdd(&deg[dst[i]], 1);
}

__global__ void k_scan1(const int* __restrict__ deg, int* __restrict__ tmp,
                        int* __restrict__ partials, int N) {
    int t = threadIdx.x, b = blockIdx.x;
    int i = b * 256 + t;
    int v = (i < N) ? deg[i] : 0;
    int lane = t & 63, w = t >> 6;
    int incl = wave_incl_scan(v, lane);
    __shared__ int wsum[4];
    if (lane == 63) wsum[w] = incl;
    __syncthreads();
    int off = 0;
    for (int j = 0; j < w; ++j) off += wsum[j];
    incl += off;
    if (i < N) tmp[i] = incl;
    if (t == 255) partials[b] = incl;
}

__global__ void k_scan2(int* __restrict__ partials, int nb) {
    int t = threadIdx.x;                   // 512 threads, nb <= 512
    int v = (t < nb) ? partials[t] : 0;
    int lane = t & 63, w = t >> 6;
    int incl = wave_incl_scan(v, lane);
    __shared__ int wsum[8];
    if (lane == 63) wsum[w] = incl;
    __syncthreads();
    int off = 0;
    for (int j = 0; j < w; ++j) off += wsum[j];
    incl += off;
    if (t < nb) partials[t] = incl;
}

__global__ void k_scan3(const int* __restrict__ tmp, const int* __restrict__ deg,
                        const int* __restrict__ partials, int* __restrict__ rowptr,
                        int* __restrict__ cur, int N) {
    int i = blockIdx.x * blockDim.x + threadIdx.x;
    if (i >= N) return;
    int b = i >> 8;
    int off = b ? partials[b - 1] : 0;
    int incl = tmp[i] + off;
    rowptr[i + 1] = incl;
    cur[i] = incl - deg[i];
    if (i == 0) rowptr[0] = 0;
}

__global__ void k_scatter(const int* __restrict__ src, const int* __restrict__ dst,
                          int* __restrict__ cur, int* __restrict__ csrc, int E) {
    int i = blockIdx.x * blockDim.x + threadIdx.x;
    if (i >= E) return;
    int pos = atomicAdd(&cur[dst[i]], 1);
    csrc[pos] = src[i];
}

// ---------------- feat = x @ W (bf16 out), plus el/er (fp32) ----------------
// block = 192 threads = 3 waves (wave == head). Each thread keeps its W column
// (64 floats) in VGPRs; 16 nodes staged in LDS per block.
__global__ __launch_bounds__(192) void k_feat(
        const float* __restrict__ xin, const int* __restrict__ ids,
        const float* __restrict__ Wemb, const float* __restrict__ W,
        const float* __restrict__ al, const float* __restrict__ ar,
        unsigned short* __restrict__ feat, float* __restrict__ el,
        float* __restrict__ er, int N) {
    int t = threadIdx.x;
    int hd = t >> 6, d = t & 63;
    float wcol[64];
#pragma unroll
    for (int k = 0; k < 64; ++k) wcol[k] = W[k * FDIM + t];
    float a_l = al[hd * HD + d], a_r = ar[hd * HD + d];

    __shared__ float xs[FEAT_NPB][HD];
    int base = blockIdx.x * FEAT_NPB;
    for (int i = t; i < FEAT_NPB * HD; i += 192) {
        int n = base + (i >> 6);
        int c = i & 63;
        float v = 0.f;
        if (n < N) v = ids ? Wemb[(size_t)ids[n] * HD + c] : xin[(size_t)n * HD + c];
        xs[i >> 6][c] = v;
    }
    __syncthreads();

    for (int i = 0; i < FEAT_NPB; ++i) {
        int n = base + i;
        if (n >= N) break;
        const float4* xv4 = (const float4*)xs[i];
        float acc = 0.f;
#pragma unroll
        for (int k4 = 0; k4 < 16; ++k4) {
            float4 xv = xv4[k4];
            acc = fmaf(xv.x, wcol[4 * k4 + 0], acc);
            acc = fmaf(xv.y, wcol[4 * k4 + 1], acc);
            acc = fmaf(xv.z, wcol[4 * k4 + 2], acc);
            acc = fmaf(xv.w, wcol[4 * k4 + 3], acc);
        }
        feat[(size_t)n * FDIM + t] = f2bf(acc);
        float pl = acc * a_l, pr = acc * a_r;
#pragma unroll
        for (int off = 32; off; off >>= 1) {
            pl += __shfl_down(pl, off);
            pr += __shfl_down(pr, off);
        }
        if (d == 0) { el[n * HEADS + hd] = pl; er[n * HEADS + hd] = pr; }
    }
}

// ---------------- gather aggregation + finalize (edge softmax, fused) ---------
// one wave per node, lane = d. Loops incoming edges via CSR. feat is bf16.
__global__ void k_gather_agg(const int* __restrict__ rowptr, const int* __restrict__ csrc,
                             const float* __restrict__ el, const float* __restrict__ er,
                             const unsigned short* __restrict__ feat,
                             const float* __restrict__ b,
                             float* __restrict__ xout, int N) {
    int wid = (blockIdx.x * blockDim.x + threadIdx.x) >> 6; // node
    int lane = threadIdx.x & 63;
    if (wid >= N) return;
    int beg = rowptr[wid], end = rowptr[wid + 1];
    float er0 = er[wid * HEADS + 0];
    float er1 = er[wid * HEADS + 1];
    float er2 = er[wid * HEADS + 2];
    float acc0 = 0.f, acc1 = 0.f, acc2 = 0.f;
    float ds0 = 0.f, ds1 = 0.f, ds2 = 0.f;
#pragma unroll 2
    for (int j = beg; j < end; ++j) {
        int s = csrc[j];
        const unsigned short* frow = feat + (size_t)s * FDIM;
        float e0 = el[s * HEADS + 0] + er0; e0 = e0 >= 0.f ? e0 : 0.2f * e0;
        float e1 = el[s * HEADS + 1] + er1; e1 = e1 >= 0.f ? e1 : 0.2f * e1;
        float e2 = el[s * HEADS + 2] + er2; e2 = e2 >= 0.f ? e2 : 0.2f * e2;
        float w0 = __expf(e0), w1 = __expf(e1), w2 = __expf(e2);
        acc0 = fmaf(w0, bf2f(frow[lane]), acc0);
        acc1 = fmaf(w1, bf2f(frow[HD + lane]), acc1);
        acc2 = fmaf(w2, bf2f(frow[2 * HD + lane]), acc2);
        ds0 += w0; ds1 += w1; ds2 += w2;
    }
    float o = (acc0 / fmaxf(ds0, 1e-9f) + b[lane])
            + (acc1 / fmaxf(ds1, 1e-9f) + b[HD + lane])
            + (acc2 / fmaxf(ds2, 1e-9f) + b[2 * HD + lane]);
    xout[(size_t)wid * HD + lane] = o * (1.f / 3.f);
}

// ---------------- per-graph max pooling ----------------
__global__ void k_gmax_init(unsigned int* __restrict__ gm) {
    int i = blockIdx.x * blockDim.x + threadIdx.x;
    if (i < NUM_GRAPHS * HD) gm[i] = 0x007FFFFFu; // fmap(-inf)
}

__global__ void k_gmax(const float* __restrict__ x, const int* __restrict__ gid,
                       unsigned int* __restrict__ gm, int N) {
    int lane = threadIdx.x; // 64 threads, lane = d
    int base = blockIdx.x * 64;
    int endn = min(base + 64, N);
    int cur = -1;
    float m = 0.f;
    for (int n = base; n < endn; ++n) {
        int g = gid[n];
        float v = x[(size_t)n * HD + lane];
        if (g != cur) {
            if (cur >= 0) atomicMax(&gm[cur * HD + lane], fmap(m));
            cur = g; m = v;
        } else {
            m = fmaxf(m, v);
        }
    }
    if (cur >= 0) atomicMax(&gm[cur * HD + lane], fmap(m));
}

__global__ void k_gmax_final(const unsigned int* __restrict__ gm, float* __restrict__ out) {
    int i = blockIdx.x * blockDim.x + threadIdx.x;
    if (i < NUM_GRAPHS * HD) out[i] = funmap(gm[i]);
}

// ---------------- launch ----------------
extern "C" void kernel_launch(void* const* d_in, const int* in_sizes, int n_in,
                              void* d_out, int out_size, void* d_ws, size_t ws_size,
                              hipStream_t stream) {
    const int*   node_ids = (const int*)d_in[0];
    const int*   edge_src = (const int*)d_in[1];
    const int*   edge_dst = (const int*)d_in[2];
    const int*   gid      = (const int*)d_in[3];
    const float* Wemb     = (const float*)d_in[4];
    const float* W1  = (const float*)d_in[5];
    const float* al1 = (const float*)d_in[6];
    const float* ar1 = (const float*)d_in[7];
    const float* b1  = (const float*)d_in[8];
    const float* W2  = (const float*)d_in[9];
    const float* al2 = (const float*)d_in[10];
    const float* ar2 = (const float*)d_in[11];
    const float* b2  = (const float*)d_in[12];

    int N = in_sizes[0];
    int E = in_sizes[1];

    // workspace layout
    char* p = (char*)d_ws;
    auto alloc = [&](size_t bytes) {
        char* r = p;
        p += (bytes + 255) & ~(size_t)255;
        return (void*)r;
    };
    int*   deg      = (int*)alloc((size_t)N * 4);
    int*   tmp      = (int*)alloc((size_t)N * 4);
    int*   partials = (int*)alloc(512 * 4);
    int*   rowptr   = (int*)alloc((size_t)(N + 1) * 4);
    int*   cur      = (int*)alloc((size_t)N * 4);
    int*   csrc     = (int*)alloc((size_t)E * 4);
    unsigned short* feat = (unsigned short*)alloc((size_t)N * FDIM * 2);
    float* el       = (float*)alloc((size_t)N * HEADS * 4);
    float* er       = (float*)alloc((size_t)N * HEADS * 4);
    float* x1       = (float*)alloc((size_t)N * HD * 4);
    unsigned int* gm = (unsigned int*)alloc(NUM_GRAPHS * HD * 4);
    (void)ws_size;

    // ---- CSR build (by dst) ----
    hipMemsetAsync(deg, 0, (size_t)N * 4, stream);
    k_hist<<<dim3((E + 255) / 256), dim3(256), 0, stream>>>(edge_dst, deg, E);
    int nb = (N + 255) / 256;
    k_scan1<<<dim3(nb), dim3(256), 0, stream>>>(deg, tmp, partials, N);
    k_scan2<<<dim3(1), dim3(512), 0, stream>>>(partials, nb);
    k_scan3<<<dim3((N + 255) / 256), dim3(256), 0, stream>>>(tmp, deg, partials, rowptr, cur, N);
    k_scatter<<<dim3((E + 255) / 256), dim3(256), 0, stream>>>(edge_src, edge_dst, cur, csrc, E);

    dim3 featGrid((N + FEAT_NPB - 1) / FEAT_NPB), featBlk(192);
    dim3 aggGrid((N * 64 + 255) / 256), aggBlk(256);

    // ---- layer 1 (x = embedding gather, fused) ----
    k_feat<<<featGrid, featBlk, 0, stream>>>(nullptr, node_ids, Wemb, W1, al1, ar1,
                                             feat, el, er, N);
    k_gather_agg<<<aggGrid, aggBlk, 0, stream>>>(rowptr, csrc, el, er, feat, b1, x1, N);

    // ---- layer 2 ----
    k_feat<<<featGrid, featBlk, 0, stream>>>(x1, nullptr, nullptr, W2, al2, ar2,
                                             feat, el, er, N);
    k_gather_agg<<<aggGrid, aggBlk, 0, stream>>>(rowptr, csrc, el, er, feat, b2, x1, N);

    // ---- per-graph max pooling ----
    k_gmax_init<<<dim3(1), dim3(NUM_GRAPHS * HD), 0, stream>>>(gm);
    k_gmax<<<dim3((N + 63) / 64), dim3(64), 0, stream>>>(x1, gid, gm, N);
    k_gmax_final<<<dim3(1), dim3(NUM_GRAPHS * HD), 0, stream>>>(gm, (float*)d_out);
}

// Round 3
// 419.910 us; speedup vs baseline: 1.4122x; 1.1927x over previous
//
#include <hip/hip_runtime.h>
#include <math.h>

// GAT aggregator: embed-gather -> GAT layer1 -> GAT layer2 -> per-graph max pool.
// feat GEMM via bf16 MFMA; per-edge softmax weights precomputed once per edge.

#define HEADS 3
#define HD 64
#define FDIM (HEADS*HD)   // 192
#define NUM_GRAPHS 10
#define NPB 32            // nodes per feat block

typedef short bf16x8 __attribute__((ext_vector_type(8)));
typedef float f32x4  __attribute__((ext_vector_type(4)));

// ---------------- bf16 helpers ----------------
__device__ __forceinline__ float bf2f(unsigned short u) {
    return __uint_as_float(((unsigned int)u) << 16);
}
__device__ __forceinline__ unsigned short f2bf(float f) {
    unsigned int u = __float_as_uint(f);
    unsigned int r = (u + 0x7FFFu + ((u >> 16) & 1u)) >> 16;  // RNE
    return (unsigned short)r;
}

// ---------------- wave helpers ----------------
__device__ __forceinline__ int wave_incl_scan(int v, int lane) {
#pragma unroll
    for (int off = 1; off < 64; off <<= 1) {
        int t = __shfl_up(v, off);
        if (lane >= off) v += t;
    }
    return v;
}

__device__ __forceinline__ unsigned int fmap(float f) {
    unsigned int u = __float_as_uint(f);
    return (u & 0x80000000u) ? ~u : (u | 0x80000000u);
}
__device__ __forceinline__ float funmap(unsigned int u) {
    u = (u & 0x80000000u) ? (u & 0x7FFFFFFFu) : ~u;
    return __uint_as_float(u);
}

// ---------------- W pre-transpose to bf16: Wt[c][k] = W[k][c] ----------------
__global__ void k_wprep(const float* __restrict__ W1, const float* __restrict__ W2,
                        unsigned short* __restrict__ Wt1, unsigned short* __restrict__ Wt2) {
    int i = blockIdx.x * blockDim.x + threadIdx.x;   // 2*12288
    const float* W = (i < FDIM * HD) ? W1 : W2;
    unsigned short* Wt = (i < FDIM * HD) ? Wt1 : Wt2;
    int j = i % (FDIM * HD);
    int c = j >> 6, k = j & 63;
    Wt[j] = f2bf(W[k * FDIM + c]);
}

// ---------------- CSR build ----------------
__global__ void k_hist(const int* __restrict__ dst, int* __restrict__ deg, int E) {
    int i = blockIdx.x * blockDim.x + threadIdx.x;
    if (i < E) atomicAdd(&deg[dst[i]], 1);
}

__global__ void k_scan1(const int* __restrict__ deg, int* __restrict__ tmp,
                        int* __restrict__ partials, int N) {
    int t = threadIdx.x, b = blockIdx.x;
    int i = b * 256 + t;
    int v = (i < N) ? deg[i] : 0;
    int lane = t & 63, w = t >> 6;
    int incl = wave_incl_scan(v, lane);
    __shared__ int wsum[4];
    if (lane == 63) wsum[w] = incl;
    __syncthreads();
    int off = 0;
    for (int j = 0; j < w; ++j) off += wsum[j];
    incl += off;
    if (i < N) tmp[i] = incl;
    if (t == 255) partials[b] = incl;
}

__global__ void k_scan2(int* __restrict__ partials, int nb) {
    int t = threadIdx.x;                   // 512 threads, nb <= 512
    int v = (t < nb) ? partials[t] : 0;
    int lane = t & 63, w = t >> 6;
    int incl = wave_incl_scan(v, lane);
    __shared__ int wsum[8];
    if (lane == 63) wsum[w] = incl;
    __syncthreads();
    int off = 0;
    for (int j = 0; j < w; ++j) off += wsum[j];
    incl += off;
    if (t < nb) partials[t] = incl;
}

__global__ void k_scan3(const int* __restrict__ tmp, const int* __restrict__ deg,
                        const int* __restrict__ partials, int* __restrict__ rowptr,
                        int* __restrict__ cur1, int* __restrict__ cur2, int N) {
    int i = blockIdx.x * blockDim.x + threadIdx.x;
    if (i >= N) return;
    int b = i >> 8;
    int off = b ? partials[b - 1] : 0;
    int incl = tmp[i] + off;
    rowptr[i + 1] = incl;
    int start = incl - deg[i];
    cur1[i] = start;
    cur2[i] = start;
    if (i == 0) rowptr[0] = 0;
}

// ---------------- feat = x @ W via MFMA; el/er fused ----------------
// block: 256 threads = 4 waves; 32 nodes. Wave w computes col-tiles [w*48, w*48+48).
__global__ __launch_bounds__(256) void k_feat_mfma(
        const float* __restrict__ xin, const int* __restrict__ ids,
        const float* __restrict__ Wemb, const unsigned short* __restrict__ Wt,
        const float* __restrict__ al, const float* __restrict__ ar,
        unsigned short* __restrict__ feat, float* __restrict__ el,
        float* __restrict__ er, int N) {
    __shared__ unsigned short xs[NPB][72];    // A tile, padded (bank-safe)
    __shared__ unsigned short ls[NPB][200];   // C tile, padded
    int t = threadIdx.x;
    int lane = t & 63, w = t >> 6;
    int base = blockIdx.x * NPB;

    // stage A (x -> bf16 LDS)
    for (int i = t; i < NPB * HD; i += 256) {
        int row = i >> 6, col = i & 63;
        int n = base + row;
        float v = 0.f;
        if (n < N) v = ids ? Wemb[(size_t)ids[n] * HD + col] : xin[(size_t)n * HD + col];
        xs[row][col] = f2bf(v);
    }

    // B fragments: Wt[c][k], lane: col=l&15, k0=(l>>4)*8
    bf16x8 bfrag[3][2];
#pragma unroll
    for (int c = 0; c < 3; ++c)
#pragma unroll
        for (int kk = 0; kk < 2; ++kk) {
            int coln = w * 48 + c * 16 + (lane & 15);
            int k0 = kk * 32 + (lane >> 4) * 8;
            bfrag[c][kk] = *(const bf16x8*)(Wt + (size_t)coln * HD + k0);
        }
    __syncthreads();

    // MFMA: 2 row-tiles x 3 col-tiles, K=64 (2 steps)
    f32x4 acc[2][3];
#pragma unroll
    for (int r = 0; r < 2; ++r)
#pragma unroll
        for (int c = 0; c < 3; ++c) acc[r][c] = (f32x4){0.f, 0.f, 0.f, 0.f};
#pragma unroll
    for (int r = 0; r < 2; ++r)
#pragma unroll
        for (int kk = 0; kk < 2; ++kk) {
            int row = r * 16 + (lane & 15);
            int k0 = kk * 32 + (lane >> 4) * 8;
            bf16x8 a = *(const bf16x8*)(&xs[row][k0]);
#pragma unroll
            for (int c = 0; c < 3; ++c)
                acc[r][c] = __builtin_amdgcn_mfma_f32_16x16x32_bf16(a, bfrag[c][kk], acc[r][c], 0, 0, 0);
        }

    // C -> LDS (bf16). C/D: col=lane&15, row=(lane>>4)*4+reg
#pragma unroll
    for (int r = 0; r < 2; ++r)
#pragma unroll
        for (int c = 0; c < 3; ++c) {
            int col = w * 48 + c * 16 + (lane & 15);
#pragma unroll
            for (int j = 0; j < 4; ++j) {
                int row = r * 16 + (lane >> 4) * 4 + j;
                ls[row][col] = f2bf(acc[r][c][j]);
            }
        }
    __syncthreads();

    // coalesced feat store (ushort4 units)
    for (int i = t; i < NPB * FDIM / 4; i += 256) {
        int idx = i * 4;
        int row = idx / FDIM, col = idx % FDIM;
        int n = base + row;
        if (n < N) {
            ushort4 v = *(const ushort4*)(&ls[row][col]);
            *(ushort4*)(feat + (size_t)n * FDIM + col) = v;
        }
    }

    // el/er: wave w handles nodes [w*8, w*8+8)
    float a0 = al[lane], a1 = al[HD + lane], a2 = al[2 * HD + lane];
    float r0 = ar[lane], r1 = ar[HD + lane], r2 = ar[2 * HD + lane];
    for (int i = 0; i < 8; ++i) {
        int row = w * 8 + i;
        int n = base + row;
        if (n >= N) break;
        float f0 = bf2f(ls[row][lane]);
        float f1 = bf2f(ls[row][HD + lane]);
        float f2v = bf2f(ls[row][2 * HD + lane]);
        float v0 = f0 * a0, v1 = f1 * a1, v2 = f2v * a2;
        float v3 = f0 * r0, v4 = f1 * r1, v5 = f2v * r2;
#pragma unroll
        for (int off = 32; off; off >>= 1) {
            v0 += __shfl_xor(v0, off); v1 += __shfl_xor(v1, off); v2 += __shfl_xor(v2, off);
            v3 += __shfl_xor(v3, off); v4 += __shfl_xor(v4, off); v5 += __shfl_xor(v5, off);
        }
        if (lane == 0) {
            el[n * HEADS + 0] = v0; el[n * HEADS + 1] = v1; el[n * HEADS + 2] = v2;
            er[n * HEADS + 0] = v3; er[n * HEADS + 1] = v4; er[n * HEADS + 2] = v5;
        }
    }
}

// ---------------- per-edge weights + CSR scatter (fused) ----------------
__global__ void k_edgew_scatter(const int* __restrict__ src, const int* __restrict__ dst,
                                const float* __restrict__ el, const float* __restrict__ er,
                                int* __restrict__ cur, float4* __restrict__ ew, int E) {
    int i = blockIdx.x * blockDim.x + threadIdx.x;
    if (i >= E) return;
    int s = src[i], d = dst[i];
    float e0 = el[s * HEADS + 0] + er[d * HEADS + 0]; e0 = e0 >= 0.f ? e0 : 0.2f * e0;
    float e1 = el[s * HEADS + 1] + er[d * HEADS + 1]; e1 = e1 >= 0.f ? e1 : 0.2f * e1;
    float e2 = el[s * HEADS + 2] + er[d * HEADS + 2]; e2 = e2 >= 0.f ? e2 : 0.2f * e2;
    int pos = atomicAdd(&cur[d], 1);
    float4 o;
    o.x = __int_as_float(s);
    o.y = __expf(e0); o.z = __expf(e1); o.w = __expf(e2);
    ew[pos] = o;
}

// ---------------- gather aggregation + finalize ----------------
__global__ void k_gather(const int* __restrict__ rowptr, const float4* __restrict__ ew,
                         const unsigned short* __restrict__ feat,
                         const float* __restrict__ b,
                         float* __restrict__ xout, int N) {
    int wid = (blockIdx.x * blockDim.x + threadIdx.x) >> 6; // node
    int lane = threadIdx.x & 63;
    if (wid >= N) return;
    int beg = rowptr[wid], end = rowptr[wid + 1];
    float acc0 = 0.f, acc1 = 0.f, acc2 = 0.f;
    float ds0 = 0.f, ds1 = 0.f, ds2 = 0.f;
#pragma unroll 4
    for (int j = beg; j < end; ++j) {
        float4 e = ew[j];
        int s = __float_as_int(e.x);
        const unsigned short* frow = feat + (size_t)s * FDIM;
        acc0 = fmaf(e.y, bf2f(frow[lane]), acc0);
        acc1 = fmaf(e.z, bf2f(frow[HD + lane]), acc1);
        acc2 = fmaf(e.w, bf2f(frow[2 * HD + lane]), acc2);
        ds0 += e.y; ds1 += e.z; ds2 += e.w;
    }
    float o = (acc0 / fmaxf(ds0, 1e-9f) + b[lane])
            + (acc1 / fmaxf(ds1, 1e-9f) + b[HD + lane])
            + (acc2 / fmaxf(ds2, 1e-9f) + b[2 * HD + lane]);
    xout[(size_t)wid * HD + lane] = o * (1.f / 3.f);
}

// ---------------- per-graph max pooling ----------------
__global__ void k_gmax_init(unsigned int* __restrict__ gm) {
    int i = blockIdx.x * blockDim.x + threadIdx.x;
    if (i < NUM_GRAPHS * HD) gm[i] = 0x007FFFFFu;
}

__global__ void k_gmax(const float* __restrict__ x, const int* __restrict__ gid,
                       unsigned int* __restrict__ gm, int N) {
    int lane = threadIdx.x;
    int base = blockIdx.x * 64;
    int endn = min(base + 64, N);
    int cur = -1;
    float m = 0.f;
    for (int n = base; n < endn; ++n) {
        int g = gid[n];
        float v = x[(size_t)n * HD + lane];
        if (g != cur) {
            if (cur >= 0) atomicMax(&gm[cur * HD + lane], fmap(m));
            cur = g; m = v;
        } else {
            m = fmaxf(m, v);
        }
    }
    if (cur >= 0) atomicMax(&gm[cur * HD + lane], fmap(m));
}

__global__ void k_gmax_final(const unsigned int* __restrict__ gm, float* __restrict__ out) {
    int i = blockIdx.x * blockDim.x + threadIdx.x;
    if (i < NUM_GRAPHS * HD) out[i] = funmap(gm[i]);
}

// ---------------- launch ----------------
extern "C" void kernel_launch(void* const* d_in, const int* in_sizes, int n_in,
                              void* d_out, int out_size, void* d_ws, size_t ws_size,
                              hipStream_t stream) {
    const int*   node_ids = (const int*)d_in[0];
    const int*   edge_src = (const int*)d_in[1];
    const int*   edge_dst = (const int*)d_in[2];
    const int*   gid      = (const int*)d_in[3];
    const float* Wemb     = (const float*)d_in[4];
    const float* W1  = (const float*)d_in[5];
    const float* al1 = (const float*)d_in[6];
    const float* ar1 = (const float*)d_in[7];
    const float* b1  = (const float*)d_in[8];
    const float* W2  = (const float*)d_in[9];
    const float* al2 = (const float*)d_in[10];
    const float* ar2 = (const float*)d_in[11];
    const float* b2  = (const float*)d_in[12];

    int N = in_sizes[0];
    int E = in_sizes[1];

    char* p = (char*)d_ws;
    auto alloc = [&](size_t bytes) {
        char* r = p;
        p += (bytes + 255) & ~(size_t)255;
        return (void*)r;
    };
    int*   deg      = (int*)alloc((size_t)N * 4);
    int*   tmp      = (int*)alloc((size_t)N * 4);
    int*   partials = (int*)alloc(512 * 4);
    int*   rowptr   = (int*)alloc((size_t)(N + 1) * 4);
    int*   cur1     = (int*)alloc((size_t)N * 4);
    int*   cur2     = (int*)alloc((size_t)N * 4);
    float4* ew      = (float4*)alloc((size_t)E * 16);
    unsigned short* feat = (unsigned short*)alloc((size_t)N * FDIM * 2);
    unsigned short* Wt1  = (unsigned short*)alloc((size_t)FDIM * HD * 2);
    unsigned short* Wt2  = (unsigned short*)alloc((size_t)FDIM * HD * 2);
    float* el       = (float*)alloc((size_t)N * HEADS * 4);
    float* er       = (float*)alloc((size_t)N * HEADS * 4);
    float* x1       = (float*)alloc((size_t)N * HD * 4);
    unsigned int* gm = (unsigned int*)alloc(NUM_GRAPHS * HD * 4);
    (void)ws_size;

    // ---- weight prep + CSR build ----
    k_wprep<<<dim3((2 * FDIM * HD + 255) / 256), dim3(256), 0, stream>>>(W1, W2, Wt1, Wt2);
    hipMemsetAsync(deg, 0, (size_t)N * 4, stream);
    k_hist<<<dim3((E + 255) / 256), dim3(256), 0, stream>>>(edge_dst, deg, E);
    int nb = (N + 255) / 256;
    k_scan1<<<dim3(nb), dim3(256), 0, stream>>>(deg, tmp, partials, N);
    k_scan2<<<dim3(1), dim3(512), 0, stream>>>(partials, nb);
    k_scan3<<<dim3(nb), dim3(256), 0, stream>>>(tmp, deg, partials, rowptr, cur1, cur2, N);

    dim3 featGrid((N + NPB - 1) / NPB), featBlk(256);
    dim3 aggGrid((N * 64 + 255) / 256), aggBlk(256);
    dim3 eGrid((E + 255) / 256), eBlk(256);

    // ---- layer 1 ----
    k_feat_mfma<<<featGrid, featBlk, 0, stream>>>(nullptr, node_ids, Wemb, Wt1, al1, ar1,
                                                  feat, el, er, N);
    k_edgew_scatter<<<eGrid, eBlk, 0, stream>>>(edge_src, edge_dst, el, er, cur1, ew, E);
    k_gather<<<aggGrid, aggBlk, 0, stream>>>(rowptr, ew, feat, b1, x1, N);

    // ---- layer 2 ----
    k_feat_mfma<<<featGrid, featBlk, 0, stream>>>(x1, nullptr, nullptr, Wt2, al2, ar2,
                                                  feat, el, er, N);
    k_edgew_scatter<<<eGrid, eBlk, 0, stream>>>(edge_src, edge_dst, el, er, cur2, ew, E);
    k_gather<<<aggGrid, aggBlk, 0, stream>>>(rowptr, ew, feat, b2, x1, N);

    // ---- per-graph max pooling ----
    k_gmax_init<<<dim3(1), dim3(NUM_GRAPHS * HD), 0, stream>>>(gm);
    k_gmax<<<dim3((N + 63) / 64), dim3(64), 0, stream>>>(x1, gid, gm, N);
    k_gmax_final<<<dim3(1), dim3(NUM_GRAPHS * HD), 0, stream>>>(gm, (float*)d_out);
}